// Round 20
// baseline (805.391 us; speedup 1.0000x reference)
//
#include <hip/hip_runtime.h>

typedef __attribute__((ext_vector_type(8))) short bf16x8;
typedef __attribute__((ext_vector_type(4))) float f32x4;

__device__ __forceinline__ unsigned short f2bf(float x){
  union { float f; unsigned u; } v; v.f = x;
  unsigned r = v.u + 0x7FFFu + ((v.u >> 16) & 1u);
  return (unsigned short)(r >> 16);
}

// fast sigmoid/tanh via v_exp_f32 (2^x, ~1ulp)
__device__ __forceinline__ float sigm(float x){
  return 1.f / (1.f + __builtin_amdgcn_exp2f(-1.44269504f * x));
}
__device__ __forceinline__ float tanhfast(float x){
  return 2.f / (1.f + __builtin_amdgcn_exp2f(-2.88539008f * x)) - 1.f;
}

#define BYPASS_ST_SHORT(base, val) \
  asm volatile("global_store_short %0, %1, off sc0 sc1" :: "v"(base), "v"(val))

__device__ __forceinline__ int ld_flag(const int* p){
  int v;
  asm volatile("global_load_dword %0, %1, off sc0 sc1\n\t"
               "s_waitcnt vmcnt(0)"
               : "=v"(v) : "v"(p) : "memory");
  return v;
}

__device__ __forceinline__ void gload_lds16(const void* g, void* l){
  __builtin_amdgcn_global_load_lds(
      (const __attribute__((address_space(1))) unsigned*)g,
      (__attribute__((address_space(3))) unsigned*)l, 16, 0, 0);
}

// ---------------- merged embed (blocks 0..259) + weight-prep (blocks 260..515) -------
__global__ __launch_bounds__(512) void embed_prep(
    const int* __restrict__ seqs, const float* __restrict__ emb,
    unsigned short* __restrict__ x, int* __restrict__ mask, int* __restrict__ flags,
    const float* __restrict__ fk0, unsigned short* __restrict__ fk0T,
    const float* __restrict__ fr0, unsigned short* __restrict__ fr0T,
    const float* __restrict__ fk1, unsigned short* __restrict__ fk1T,
    const float* __restrict__ fr1, unsigned short* __restrict__ fr1T,
    const float* __restrict__ bk0, unsigned short* __restrict__ bk0T,
    const float* __restrict__ br0, unsigned short* __restrict__ br0T,
    const float* __restrict__ bk1, unsigned short* __restrict__ bk1T,
    const float* __restrict__ br1, unsigned short* __restrict__ br1T)
{
  __shared__ float tf[32*65];
  const int blk = blockIdx.x, tid = threadIdx.x;
  if (blk < 260){
    if (blk == 0 && tid < 64){
      #pragma unroll
      for (int j = 0; j < 16; ++j) flags[tid + j*64] = 0;   // 64 slots x 64B
    }
    const int idx = blk*8 + (tid >> 6);
    const int lane = tid & 63;
    const int b = idx / 130, t = idx - b*130;
    const int tok = seqs[b*130 + t];
    if (lane == 0) mask[b*130 + t] = (tok != 0) ? 1 : 0;
    const float* src = emb + (size_t)tok * 256;
    unsigned short* dst = x + ((size_t)b*130 + t)*256;
    #pragma unroll
    for (int j = 0; j < 4; ++j) dst[lane + j*64] = f2bf(src[lane + j*64]);
    return;
  }
  // ---- weight transpose arm: 3584 tiles of [32 k][64 n] ----
  const int tx = tid & 63, ty = tid >> 6;           // 64 x 8 load
  const int orow = tid & 31, oc = tid >> 5;         // 32 x 16 store
  for (int tile = blk - 260; tile < 3584; tile += 256){
    const float* src; unsigned short* dst; int R;
    int u = tile;
    if (u < 256)      { src = fk0; dst = fk0T; R = 256;           }
    else if (u < 768) { src = fr0; dst = fr0T; R = 512; u -= 256; }
    else if (u < 1280){ src = fk1; dst = fk1T; R = 512; u -= 768; }
    else if (u < 1792){ src = fr1; dst = fr1T; R = 512; u -= 1280;}
    else if (u < 2048){ src = bk0; dst = bk0T; R = 256; u -= 1792;}
    else if (u < 2560){ src = br0; dst = br0T; R = 512; u -= 2048;}
    else if (u < 3072){ src = bk1; dst = bk1T; R = 512; u -= 2560;}
    else              { src = br1; dst = br1T; R = 512; u -= 3072;}
    const int kt = u >> 5, nt = u & 31;             // 2048/64 = 32 col-tiles
    const int r0 = kt*32, c0 = nt*64;
    #pragma unroll
    for (int j = 0; j < 4; ++j)
      tf[(ty + 8*j)*65 + tx] = src[(size_t)(r0 + ty + 8*j)*2048 + c0 + tx];
    __syncthreads();
    #pragma unroll
    for (int j = 0; j < 4; ++j)
      dst[(size_t)(c0 + oc + 16*j)*R + r0 + orow] = f2bf(tf[orow*65 + oc + 16*j]);
    __syncthreads();
  }
}

// ---------------- fused: persistent LSTM (wg 0..63) + Wp transpose (wg 64..159) ------
// (R20 verbatim — 578us proven fused)
__global__ __launch_bounds__(512, 2) void lstm_coop(
    const unsigned short* __restrict__ x, const int* __restrict__ maskg,
    const unsigned short* __restrict__ fk0T, const unsigned short* __restrict__ fr0T,
    const unsigned short* __restrict__ fk1T, const unsigned short* __restrict__ fr1T,
    const unsigned short* __restrict__ bk0T, const unsigned short* __restrict__ br0T,
    const unsigned short* __restrict__ bk1T, const unsigned short* __restrict__ br1T,
    const float* __restrict__ fb0, const float* __restrict__ fb1,
    const float* __restrict__ bb0, const float* __restrict__ bb1,
    const float* __restrict__ Wp, unsigned short* __restrict__ WpT,
    unsigned short* h0f, unsigned short* h0b,
    unsigned short* aproj, int* flags)
{
  const int wg = blockIdx.x;
  const int tid = threadIdx.x;

  __shared__ float z_lds[4][16][32];
  __shared__ int mask_s[16*130];
  __shared__ __attribute__((aligned(16))) char h_lds[16*1024];
  __shared__ __attribute__((aligned(16))) char h2_lds[16*1024];

  if (wg >= 64){
    float* tf = (float*)h_lds;                        // overlay [32][65] floats
    const int tw = wg - 64;
    const int tx = tid & 63, ty = tid >> 6;           // 64 x 8
    const int orow = tid & 31, oc = tid >> 5;         // 32 x 16
    for (int tile = tw; tile < 16000; tile += 96){
      const int kt = tile / 500, nt = tile - kt*500;
      const int r0 = kt*32, c0 = nt*64;
      #pragma unroll
      for (int j = 0; j < 4; ++j)
        tf[(ty + 8*j)*65 + tx] = Wp[(size_t)(r0 + ty + 8*j)*32000 + c0 + tx];
      __syncthreads();
      #pragma unroll
      for (int j = 0; j < 4; ++j)
        WpT[(size_t)(c0 + oc + 16*j)*1024 + r0 + orow] = f2bf(tf[orow*65 + oc + 16*j]);
      __syncthreads();
    }
    return;
  }

  const int dir = wg >> 5;
  const int layer = (wg >> 4) & 1;
  const int u0 = (wg & 15) * 32;
  const int w = tid >> 6, l = tid & 63;
  const int gate = w >> 1, half = w & 1;
  const int lr = l & 15, lk = l >> 4;
  const int cglob = gate*512 + u0 + half*16 + lr;

  const unsigned short* kT = (layer == 0) ? (dir ? bk0T : fk0T) : (dir ? bk1T : fk1T);
  const unsigned short* rT = (layer == 0) ? (dir ? br0T : fr0T) : (dir ? br1T : fr1T);
  const float* bias = (layer == 0) ? (dir ? bb0 : fb0) : (dir ? bb1 : fb1);
  unsigned short* h0 = dir ? h0b : h0f;

  int* fown  = flags + (layer*2 + dir)*256;
  int* fprod = flags + dir*256;
  int* fself = fown + (wg & 15)*16;

  bf16x8 wreg[16], kreg[16];
  #pragma unroll
  for (int i = 0; i < 16; ++i)
    wreg[i] = *(const bf16x8*)(rT + (size_t)cglob*512 + i*32 + lk*8);
  if (layer == 0){
    #pragma unroll
    for (int i = 0; i < 8; ++i)
      kreg[i] = *(const bf16x8*)(kT + (size_t)cglob*256 + i*32 + lk*8);
  } else {
    #pragma unroll
    for (int i = 0; i < 16; ++i)
      kreg[i] = *(const bf16x8*)(kT + (size_t)cglob*512 + i*32 + lk*8);
  }

  for (int i = tid; i < 16*130; i += 512) mask_s[i] = maskg[i];

  float c_reg = 0.f, h_reg = 0.f;
  const int gu = tid & 31, gb = tid >> 5;
  const float bzi = bias[u0+gu], bzf = bias[512 + u0+gu];
  const float bzc = bias[1024 + u0+gu], bzo = bias[1536 + u0+gu];
  __syncthreads();

  for (int t = 0; t < 128; ++t){
    {
      const int* fp = nullptr; int tgt = 0;
      if (l < 16){ fp = fown + l*16; tgt = t; }
      else if (l < 32 && layer == 1){ fp = fprod + (l-16)*16; tgt = t + 1; }
      if (fp){
        while (ld_flag(fp) < tgt) __builtin_amdgcn_s_sleep(1);
      }
    }

    const int r0s = w*2;
    if (layer == 0){
      if (t > 0){
        #pragma unroll
        for (int j = 0; j < 2; ++j){
          const int r = r0s + j;
          const unsigned short* g = h0 + ((size_t)(t-1)*16 + r)*512 + ((l ^ (r & 7))*8);
          gload_lds16(g, h_lds + r*1024);
        }
      }
    } else {
      #pragma unroll
      for (int j = 0; j < 2; ++j){
        const int r = r0s + j;
        const unsigned short* g = h0 + ((size_t)t*16 + r)*512 + ((l ^ (r & 7))*8);
        gload_lds16(g, h_lds + r*1024);
      }
      if (t > 0){
        const int prow = dir ? (128 - t) : (t - 1);
        #pragma unroll
        for (int j = 0; j < 2; ++j){
          const int r = r0s + j;
          const unsigned short* g = aproj + ((size_t)(r*128 + prow))*1024 + dir*512 + ((l ^ (r & 7))*8);
          gload_lds16(g, h2_lds + r*1024);
        }
      }
    }

    f32x4 a0 = {0.f,0.f,0.f,0.f}, a1 = a0;
    const int fsw = (lr & 7) << 4;
    if (layer == 0){
      const int pos = dir ? (129 - t) : t;
      const unsigned short* xa = x + ((size_t)lr*130 + pos)*256 + lk*8;
      #pragma unroll
      for (int i = 0; i < 8; i += 2){
        bf16x8 va = *(const bf16x8*)(xa + i*32);
        bf16x8 vb = *(const bf16x8*)(xa + i*32 + 32);
        a0 = __builtin_amdgcn_mfma_f32_16x16x32_bf16(va, kreg[i],   a0, 0, 0, 0);
        a1 = __builtin_amdgcn_mfma_f32_16x16x32_bf16(vb, kreg[i+1], a1, 0, 0, 0);
      }
      if (t > 0){
        asm volatile("s_waitcnt vmcnt(0)" ::: "memory");
        __syncthreads();                               // S2
        #pragma unroll
        for (int i = 0; i < 16; i += 2){
          bf16x8 v0 = *(const bf16x8*)(h_lds + lr*1024 + ((lk*16 + (i  )*64) ^ fsw));
          bf16x8 v1 = *(const bf16x8*)(h_lds + lr*1024 + ((lk*16 + (i+1)*64) ^ fsw));
          a0 = __builtin_amdgcn_mfma_f32_16x16x32_bf16(v0, wreg[i],   a0, 0, 0, 0);
          a1 = __builtin_amdgcn_mfma_f32_16x16x32_bf16(v1, wreg[i+1], a1, 0, 0, 0);
        }
      }
    } else {
      asm volatile("s_waitcnt vmcnt(0)" ::: "memory");
      __syncthreads();                                 // S2
      #pragma unroll
      for (int i = 0; i < 16; i += 2){
        bf16x8 v0 = *(const bf16x8*)(h_lds + lr*1024 + ((lk*16 + (i  )*64) ^ fsw));
        bf16x8 v1 = *(const bf16x8*)(h_lds + lr*1024 + ((lk*16 + (i+1)*64) ^ fsw));
        a0 = __builtin_amdgcn_mfma_f32_16x16x32_bf16(v0, kreg[i],   a0, 0, 0, 0);
        a1 = __builtin_amdgcn_mfma_f32_16x16x32_bf16(v1, kreg[i+1], a1, 0, 0, 0);
      }
      if (t > 0){
        #pragma unroll
        for (int i = 0; i < 16; i += 2){
          bf16x8 v0 = *(const bf16x8*)(h2_lds + lr*1024 + ((lk*16 + (i  )*64) ^ fsw));
          bf16x8 v1 = *(const bf16x8*)(h2_lds + lr*1024 + ((lk*16 + (i+1)*64) ^ fsw));
          a0 = __builtin_amdgcn_mfma_f32_16x16x32_bf16(v0, wreg[i],   a0, 0, 0, 0);
          a1 = __builtin_amdgcn_mfma_f32_16x16x32_bf16(v1, wreg[i+1], a1, 0, 0, 0);
        }
      }
    }
    {
      f32x4 acc = a0 + a1;
      #pragma unroll
      for (int r = 0; r < 4; ++r) z_lds[gate][lk*4 + r][half*16 + lr] = acc[r];
    }
    __syncthreads();                                   // S3

    {
      const float zi = z_lds[0][gb][gu] + bzi;
      const float zf = z_lds[1][gb][gu] + bzf;
      const float zc = z_lds[2][gb][gu] + bzc;
      const float zo = z_lds[3][gb][gu] + bzo;
      const float iv = sigm(zi);
      const float fv = sigm(zf);
      const float ov = sigm(zo);
      const float gv = tanhfast(zc);
      float cn = fv*c_reg + iv*gv;
      float hn = ov*tanhfast(cn);
      const int pos = dir ? (129 - t) : t;
      if (mask_s[gb*130 + pos] == 0){ cn = c_reg; hn = h_reg; }
      c_reg = cn; h_reg = hn;
      const unsigned short hb = f2bf(hn);
      if (layer == 0){
        unsigned short* p = h0 + ((size_t)t*16 + gb)*512 + u0 + gu;
        BYPASS_ST_SHORT(p, (unsigned)hb);
      } else {
        const int row = dir ? (127 - t) : t;
        unsigned short* p = aproj + ((size_t)gb*128 + row)*1024 + dir*512 + u0 + gu;
        BYPASS_ST_SHORT(p, (unsigned)hb);
      }
    }
    asm volatile("s_waitcnt vmcnt(0)" ::: "memory");
    __syncthreads();                                   // S4
    if (tid == 0){
      int v = t + 1;
      asm volatile("global_store_dword %0, %1, off sc0 sc1" :: "v"(fself), "v"(v) : "memory");
    }
  }
}

// ---------------- bf16 MFMA GEMM: 256x256 tile, BK=64, 8 waves, 2 full dbuf ----------
// Stage-issue of tile t+1 spread over tile t's 4 phases (ks x m-half); one
// vmcnt(0)+barrier per K-tile. Involutive swizzle L^=((L>>7)&7)<<4 on both sides
// (rule #21). XCD-bijective M-inner grid (1000 = 8 x 125). No tails.
#define SWZ7(L) ((L) ^ ((((L) >> 7) & 7) << 4))
__global__ __launch_bounds__(512) void gemm_bf16(
    const unsigned short* __restrict__ A, const unsigned short* __restrict__ Bt,
    const float* __restrict__ bias, float* __restrict__ C,
    int M, int N, int K)
{
  __shared__ unsigned short lA[2][256*64], lB[2][256*64];   // 2 x 32KB each = 128KB
  const int tid = threadIdx.x;
  const int w = tid >> 6, l = tid & 63;
  const int wm = w >> 2, wn = w & 3;
  const int lr = l & 15, lk = l >> 4;
  const int orig = blockIdx.x;                   // 0..999; 1000 % 8 == 0 -> bijective
  const int logical = (orig & 7)*125 + (orig >> 3);
  const int mt = logical & 7;                    // M inner (8 M-tiles)
  const int nt = logical >> 3;                   // 125 N-tiles
  const int brow = mt*256, bcol = nt*256;

  f32x4 acc[8][4] = {};

  // stage chunk j (0..3) of K-tile kt_ into slot s_: 1KB of A + 1KB of B per wave
  #define STG(kt_, s_, j_) do{ \
    const int Lw = w*4096 + (j_)*1024 + l*16; \
    const int Lg = SWZ7(Lw); \
    const int rw = Lg >> 7, cb = Lg & 127; \
    gload_lds16((const char*)(A + (size_t)(brow+rw)*K + (kt_)*64) + cb, \
                (char*)lA[s_] + w*4096 + (j_)*1024); \
    gload_lds16((const char*)(Bt + (size_t)(bcol+rw)*K + (kt_)*64) + cb, \
                (char*)lB[s_] + w*4096 + (j_)*1024); \
  }while(0)

  // prologue: tile 0 -> slot 0
  #pragma unroll
  for (int j = 0; j < 4; ++j) STG(0, 0, j);
  asm volatile("s_waitcnt vmcnt(0)" ::: "memory");
  __syncthreads();

  for (int kt = 0; kt < 16; ++kt){
    const int s = kt & 1;
    #pragma unroll
    for (int p = 0; p < 4; ++p){
      if (kt < 15) STG(kt + 1, s ^ 1, p);          // prefetch issue first (overlaps)
      const int ks = p >> 1, mh = p & 1;
      bf16x8 bf[4], af[4];
      #pragma unroll
      for (int n = 0; n < 4; ++n){
        const int L = (wn*64 + n*16 + lr)*128 + ks*64 + lk*16;
        bf[n] = *(const bf16x8*)((const char*)lB[s] + SWZ7(L));
      }
      #pragma unroll
      for (int m4 = 0; m4 < 4; ++m4){
        const int L = (wm*128 + (mh*4 + m4)*16 + lr)*128 + ks*64 + lk*16;
        af[m4] = *(const bf16x8*)((const char*)lA[s] + SWZ7(L));
      }
      #pragma unroll
      for (int m4 = 0; m4 < 4; ++m4)
        #pragma unroll
        for (int n = 0; n < 4; ++n)
          acc[mh*4 + m4][n] = __builtin_amdgcn_mfma_f32_16x16x32_bf16(
              af[m4], bf[n], acc[mh*4 + m4][n], 0, 0, 0);
    }
    // tile kt+1 must be fully landed before next iteration reads slot s^1
    asm volatile("s_waitcnt vmcnt(0)" ::: "memory");
    __syncthreads();
  }
  #undef STG

  #pragma unroll
  for (int m = 0; m < 8; ++m){
    #pragma unroll
    for (int n = 0; n < 4; ++n){
      const int col = bcol + wn*64 + n*16 + lr;
      const float bv = bias[col];
      const int r0 = brow + wm*128 + m*16 + lk*4;
      #pragma unroll
      for (int r = 0; r < 4; ++r)
        C[(size_t)(r0 + r)*N + col] = acc[m][n][r] + bv;
    }
  }
}

extern "C" void kernel_launch(void* const* d_in, const int* in_sizes, int n_in,
                              void* d_out, int out_size, void* d_ws, size_t ws_size,
                              hipStream_t stream){
  (void)in_sizes; (void)n_in; (void)out_size; (void)ws_size;
  const int*   seqs = (const int*)d_in[0];
  const float* emb  = (const float*)d_in[1];
  const float* fk0  = (const float*)d_in[2];
  const float* fr0  = (const float*)d_in[3];
  const float* fb0  = (const float*)d_in[4];
  const float* fk1  = (const float*)d_in[5];
  const float* fr1  = (const float*)d_in[6];
  const float* fb1  = (const float*)d_in[7];
  const float* bk0  = (const float*)d_in[8];
  const float* br0  = (const float*)d_in[9];
  const float* bb0  = (const float*)d_in[10];
  const float* bk1  = (const float*)d_in[11];
  const float* br1  = (const float*)d_in[12];
  const float* bb1  = (const float*)d_in[13];
  const float* Wp   = (const float*)d_in[14];
  const float* bp   = (const float*)d_in[15];
  float* out = (float*)d_out;

  char* ws = (char*)d_ws;
  size_t off = 0;
  auto alloc = [&](size_t b){ size_t o = off; off += (b + 255) & ~(size_t)255; return o; };
  int* flags            = (int*)(ws + alloc(4096));
  unsigned short* x     = (unsigned short*)(ws + alloc((size_t)16*130*256*2));
  int* mask             = (int*)(ws + alloc((size_t)16*130*4));
  unsigned short* fk0T  = (unsigned short*)(ws + alloc((size_t)2048*256*2));
  unsigned short* fr0T  = (unsigned short*)(ws + alloc((size_t)2048*512*2));
  unsigned short* fk1T  = (unsigned short*)(ws + alloc((size_t)2048*512*2));
  unsigned short* fr1T  = (unsigned short*)(ws + alloc((size_t)2048*512*2));
  unsigned short* bk0T  = (unsigned short*)(ws + alloc((size_t)2048*256*2));
  unsigned short* br0T  = (unsigned short*)(ws + alloc((size_t)2048*512*2));
  unsigned short* bk1T  = (unsigned short*)(ws + alloc((size_t)2048*512*2));
  unsigned short* br1T  = (unsigned short*)(ws + alloc((size_t)2048*512*2));
  unsigned short* h0f   = (unsigned short*)(ws + alloc((size_t)128*16*512*2));
  unsigned short* h0b   = (unsigned short*)(ws + alloc((size_t)128*16*512*2));
  unsigned short* aproj = (unsigned short*)(ws + alloc((size_t)2048*1024*2));
  unsigned short* WpT   = (unsigned short*)(ws + alloc((size_t)32000*1024*2));

  embed_prep<<<516, 512, 0, stream>>>(seqs, emb, x, mask, flags,
      fk0, fk0T, fr0, fr0T, fk1, fk1T, fr1, fr1T,
      bk0, bk0T, br0, br0T, bk1, bk1T, br1, br1T);

  lstm_coop<<<160, 512, 0, stream>>>(x, mask,
      fk0T, fr0T, fk1T, fr1T, bk0T, br0T, bk1T, br1T,
      fb0, fb1, bb0, bb1, Wp, WpT, h0f, h0b, aproj, flags);

  gemm_bf16<<<1000, 512, 0, stream>>>(aproj, WpT, bp, out, 2048, 32000, 1024);
}

// Round 21
// 792.348 us; speedup vs baseline: 1.0165x; 1.0165x over previous
//
#include <hip/hip_runtime.h>

typedef __attribute__((ext_vector_type(8))) short bf16x8;
typedef __attribute__((ext_vector_type(4))) float f32x4;

__device__ __forceinline__ unsigned short f2bf(float x){
  union { float f; unsigned u; } v; v.f = x;
  unsigned r = v.u + 0x7FFFu + ((v.u >> 16) & 1u);
  return (unsigned short)(r >> 16);
}

// fast sigmoid/tanh via v_exp_f32 (2^x, ~1ulp)
__device__ __forceinline__ float sigm(float x){
  return 1.f / (1.f + __builtin_amdgcn_exp2f(-1.44269504f * x));
}
__device__ __forceinline__ float tanhfast(float x){
  return 2.f / (1.f + __builtin_amdgcn_exp2f(-2.88539008f * x)) - 1.f;
}

#define BYPASS_ST_SHORT(base, val) \
  asm volatile("global_store_short %0, %1, off sc0 sc1" :: "v"(base), "v"(val))

__device__ __forceinline__ int ld_flag(const int* p){
  int v;
  asm volatile("global_load_dword %0, %1, off sc0 sc1\n\t"
               "s_waitcnt vmcnt(0)"
               : "=v"(v) : "v"(p) : "memory");
  return v;
}

__device__ __forceinline__ void gload_lds16(const void* g, void* l){
  __builtin_amdgcn_global_load_lds(
      (const __attribute__((address_space(1))) unsigned*)g,
      (__attribute__((address_space(3))) unsigned*)l, 16, 0, 0);
}

// ---------------- merged embed (blocks 0..259) + weight-prep (blocks 260..515) -------
__global__ __launch_bounds__(512) void embed_prep(
    const int* __restrict__ seqs, const float* __restrict__ emb,
    unsigned short* __restrict__ x, int* __restrict__ mask, int* __restrict__ flags,
    const float* __restrict__ fk0, unsigned short* __restrict__ fk0T,
    const float* __restrict__ fr0, unsigned short* __restrict__ fr0T,
    const float* __restrict__ fk1, unsigned short* __restrict__ fk1T,
    const float* __restrict__ fr1, unsigned short* __restrict__ fr1T,
    const float* __restrict__ bk0, unsigned short* __restrict__ bk0T,
    const float* __restrict__ br0, unsigned short* __restrict__ br0T,
    const float* __restrict__ bk1, unsigned short* __restrict__ bk1T,
    const float* __restrict__ br1, unsigned short* __restrict__ br1T)
{
  __shared__ float tf[32*65];
  const int blk = blockIdx.x, tid = threadIdx.x;
  if (blk < 260){
    if (blk == 0 && tid < 64){
      #pragma unroll
      for (int j = 0; j < 16; ++j) flags[tid + j*64] = 0;   // 64 slots x 64B
    }
    const int idx = blk*8 + (tid >> 6);
    const int lane = tid & 63;
    const int b = idx / 130, t = idx - b*130;
    const int tok = seqs[b*130 + t];
    if (lane == 0) mask[b*130 + t] = (tok != 0) ? 1 : 0;
    const float* src = emb + (size_t)tok * 256;
    unsigned short* dst = x + ((size_t)b*130 + t)*256;
    #pragma unroll
    for (int j = 0; j < 4; ++j) dst[lane + j*64] = f2bf(src[lane + j*64]);
    return;
  }
  // ---- weight transpose arm: 3584 tiles of [32 k][64 n] ----
  const int tx = tid & 63, ty = tid >> 6;           // 64 x 8 load
  const int orow = tid & 31, oc = tid >> 5;         // 32 x 16 store
  for (int tile = blk - 260; tile < 3584; tile += 256){
    const float* src; unsigned short* dst; int R;
    int u = tile;
    if (u < 256)      { src = fk0; dst = fk0T; R = 256;           }
    else if (u < 768) { src = fr0; dst = fr0T; R = 512; u -= 256; }
    else if (u < 1280){ src = fk1; dst = fk1T; R = 512; u -= 768; }
    else if (u < 1792){ src = fr1; dst = fr1T; R = 512; u -= 1280;}
    else if (u < 2048){ src = bk0; dst = bk0T; R = 256; u -= 1792;}
    else if (u < 2560){ src = br0; dst = br0T; R = 512; u -= 2048;}
    else if (u < 3072){ src = bk1; dst = bk1T; R = 512; u -= 2560;}
    else              { src = br1; dst = br1T; R = 512; u -= 3072;}
    const int kt = u >> 5, nt = u & 31;             // 2048/64 = 32 col-tiles
    const int r0 = kt*32, c0 = nt*64;
    #pragma unroll
    for (int j = 0; j < 4; ++j)
      tf[(ty + 8*j)*65 + tx] = src[(size_t)(r0 + ty + 8*j)*2048 + c0 + tx];
    __syncthreads();
    #pragma unroll
    for (int j = 0; j < 4; ++j)
      dst[(size_t)(c0 + oc + 16*j)*R + r0 + orow] = f2bf(tf[orow*65 + oc + 16*j]);
    __syncthreads();
  }
}

// ---------------- fused: persistent LSTM (wg 0..63) + Wp transpose (wg 64..159) ------
// (R20 verbatim — 578us proven fused)
__global__ __launch_bounds__(512, 2) void lstm_coop(
    const unsigned short* __restrict__ x, const int* __restrict__ maskg,
    const unsigned short* __restrict__ fk0T, const unsigned short* __restrict__ fr0T,
    const unsigned short* __restrict__ fk1T, const unsigned short* __restrict__ fr1T,
    const unsigned short* __restrict__ bk0T, const unsigned short* __restrict__ br0T,
    const unsigned short* __restrict__ bk1T, const unsigned short* __restrict__ br1T,
    const float* __restrict__ fb0, const float* __restrict__ fb1,
    const float* __restrict__ bb0, const float* __restrict__ bb1,
    const float* __restrict__ Wp, unsigned short* __restrict__ WpT,
    unsigned short* h0f, unsigned short* h0b,
    unsigned short* aproj, int* flags)
{
  const int wg = blockIdx.x;
  const int tid = threadIdx.x;

  __shared__ float z_lds[4][16][32];
  __shared__ int mask_s[16*130];
  __shared__ __attribute__((aligned(16))) char h_lds[16*1024];
  __shared__ __attribute__((aligned(16))) char h2_lds[16*1024];

  if (wg >= 64){
    float* tf = (float*)h_lds;                        // overlay [32][65] floats
    const int tw = wg - 64;
    const int tx = tid & 63, ty = tid >> 6;           // 64 x 8
    const int orow = tid & 31, oc = tid >> 5;         // 32 x 16
    for (int tile = tw; tile < 16000; tile += 96){
      const int kt = tile / 500, nt = tile - kt*500;
      const int r0 = kt*32, c0 = nt*64;
      #pragma unroll
      for (int j = 0; j < 4; ++j)
        tf[(ty + 8*j)*65 + tx] = Wp[(size_t)(r0 + ty + 8*j)*32000 + c0 + tx];
      __syncthreads();
      #pragma unroll
      for (int j = 0; j < 4; ++j)
        WpT[(size_t)(c0 + oc + 16*j)*1024 + r0 + orow] = f2bf(tf[orow*65 + oc + 16*j]);
      __syncthreads();
    }
    return;
  }

  const int dir = wg >> 5;
  const int layer = (wg >> 4) & 1;
  const int u0 = (wg & 15) * 32;
  const int w = tid >> 6, l = tid & 63;
  const int gate = w >> 1, half = w & 1;
  const int lr = l & 15, lk = l >> 4;
  const int cglob = gate*512 + u0 + half*16 + lr;

  const unsigned short* kT = (layer == 0) ? (dir ? bk0T : fk0T) : (dir ? bk1T : fk1T);
  const unsigned short* rT = (layer == 0) ? (dir ? br0T : fr0T) : (dir ? br1T : fr1T);
  const float* bias = (layer == 0) ? (dir ? bb0 : fb0) : (dir ? bb1 : fb1);
  unsigned short* h0 = dir ? h0b : h0f;

  int* fown  = flags + (layer*2 + dir)*256;
  int* fprod = flags + dir*256;
  int* fself = fown + (wg & 15)*16;

  bf16x8 wreg[16], kreg[16];
  #pragma unroll
  for (int i = 0; i < 16; ++i)
    wreg[i] = *(const bf16x8*)(rT + (size_t)cglob*512 + i*32 + lk*8);
  if (layer == 0){
    #pragma unroll
    for (int i = 0; i < 8; ++i)
      kreg[i] = *(const bf16x8*)(kT + (size_t)cglob*256 + i*32 + lk*8);
  } else {
    #pragma unroll
    for (int i = 0; i < 16; ++i)
      kreg[i] = *(const bf16x8*)(kT + (size_t)cglob*512 + i*32 + lk*8);
  }

  for (int i = tid; i < 16*130; i += 512) mask_s[i] = maskg[i];

  float c_reg = 0.f, h_reg = 0.f;
  const int gu = tid & 31, gb = tid >> 5;
  const float bzi = bias[u0+gu], bzf = bias[512 + u0+gu];
  const float bzc = bias[1024 + u0+gu], bzo = bias[1536 + u0+gu];
  __syncthreads();

  for (int t = 0; t < 128; ++t){
    {
      const int* fp = nullptr; int tgt = 0;
      if (l < 16){ fp = fown + l*16; tgt = t; }
      else if (l < 32 && layer == 1){ fp = fprod + (l-16)*16; tgt = t + 1; }
      if (fp){
        while (ld_flag(fp) < tgt) __builtin_amdgcn_s_sleep(1);
      }
    }

    const int r0s = w*2;
    if (layer == 0){
      if (t > 0){
        #pragma unroll
        for (int j = 0; j < 2; ++j){
          const int r = r0s + j;
          const unsigned short* g = h0 + ((size_t)(t-1)*16 + r)*512 + ((l ^ (r & 7))*8);
          gload_lds16(g, h_lds + r*1024);
        }
      }
    } else {
      #pragma unroll
      for (int j = 0; j < 2; ++j){
        const int r = r0s + j;
        const unsigned short* g = h0 + ((size_t)t*16 + r)*512 + ((l ^ (r & 7))*8);
        gload_lds16(g, h_lds + r*1024);
      }
      if (t > 0){
        const int prow = dir ? (128 - t) : (t - 1);
        #pragma unroll
        for (int j = 0; j < 2; ++j){
          const int r = r0s + j;
          const unsigned short* g = aproj + ((size_t)(r*128 + prow))*1024 + dir*512 + ((l ^ (r & 7))*8);
          gload_lds16(g, h2_lds + r*1024);
        }
      }
    }

    f32x4 a0 = {0.f,0.f,0.f,0.f}, a1 = a0;
    const int fsw = (lr & 7) << 4;
    if (layer == 0){
      const int pos = dir ? (129 - t) : t;
      const unsigned short* xa = x + ((size_t)lr*130 + pos)*256 + lk*8;
      #pragma unroll
      for (int i = 0; i < 8; i += 2){
        bf16x8 va = *(const bf16x8*)(xa + i*32);
        bf16x8 vb = *(const bf16x8*)(xa + i*32 + 32);
        a0 = __builtin_amdgcn_mfma_f32_16x16x32_bf16(va, kreg[i],   a0, 0, 0, 0);
        a1 = __builtin_amdgcn_mfma_f32_16x16x32_bf16(vb, kreg[i+1], a1, 0, 0, 0);
      }
      if (t > 0){
        asm volatile("s_waitcnt vmcnt(0)" ::: "memory");
        __syncthreads();                               // S2
        #pragma unroll
        for (int i = 0; i < 16; i += 2){
          bf16x8 v0 = *(const bf16x8*)(h_lds + lr*1024 + ((lk*16 + (i  )*64) ^ fsw));
          bf16x8 v1 = *(const bf16x8*)(h_lds + lr*1024 + ((lk*16 + (i+1)*64) ^ fsw));
          a0 = __builtin_amdgcn_mfma_f32_16x16x32_bf16(v0, wreg[i],   a0, 0, 0, 0);
          a1 = __builtin_amdgcn_mfma_f32_16x16x32_bf16(v1, wreg[i+1], a1, 0, 0, 0);
        }
      }
    } else {
      asm volatile("s_waitcnt vmcnt(0)" ::: "memory");
      __syncthreads();                                 // S2
      #pragma unroll
      for (int i = 0; i < 16; i += 2){
        bf16x8 v0 = *(const bf16x8*)(h_lds + lr*1024 + ((lk*16 + (i  )*64) ^ fsw));
        bf16x8 v1 = *(const bf16x8*)(h_lds + lr*1024 + ((lk*16 + (i+1)*64) ^ fsw));
        a0 = __builtin_amdgcn_mfma_f32_16x16x32_bf16(v0, kreg[i],   a0, 0, 0, 0);
        a1 = __builtin_amdgcn_mfma_f32_16x16x32_bf16(v1, kreg[i+1], a1, 0, 0, 0);
      }
      if (t > 0){
        #pragma unroll
        for (int i = 0; i < 16; i += 2){
          bf16x8 v0 = *(const bf16x8*)(h2_lds + lr*1024 + ((lk*16 + (i  )*64) ^ fsw));
          bf16x8 v1 = *(const bf16x8*)(h2_lds + lr*1024 + ((lk*16 + (i+1)*64) ^ fsw));
          a0 = __builtin_amdgcn_mfma_f32_16x16x32_bf16(v0, wreg[i],   a0, 0, 0, 0);
          a1 = __builtin_amdgcn_mfma_f32_16x16x32_bf16(v1, wreg[i+1], a1, 0, 0, 0);
        }
      }
    }
    {
      f32x4 acc = a0 + a1;
      #pragma unroll
      for (int r = 0; r < 4; ++r) z_lds[gate][lk*4 + r][half*16 + lr] = acc[r];
    }
    __syncthreads();                                   // S3

    {
      const float zi = z_lds[0][gb][gu] + bzi;
      const float zf = z_lds[1][gb][gu] + bzf;
      const float zc = z_lds[2][gb][gu] + bzc;
      const float zo = z_lds[3][gb][gu] + bzo;
      const float iv = sigm(zi);
      const float fv = sigm(zf);
      const float ov = sigm(zo);
      const float gv = tanhfast(zc);
      float cn = fv*c_reg + iv*gv;
      float hn = ov*tanhfast(cn);
      const int pos = dir ? (129 - t) : t;
      if (mask_s[gb*130 + pos] == 0){ cn = c_reg; hn = h_reg; }
      c_reg = cn; h_reg = hn;
      const unsigned short hb = f2bf(hn);
      if (layer == 0){
        unsigned short* p = h0 + ((size_t)t*16 + gb)*512 + u0 + gu;
        BYPASS_ST_SHORT(p, (unsigned)hb);
      } else {
        const int row = dir ? (127 - t) : t;
        unsigned short* p = aproj + ((size_t)gb*128 + row)*1024 + dir*512 + u0 + gu;
        BYPASS_ST_SHORT(p, (unsigned)hb);
      }
    }
    asm volatile("s_waitcnt vmcnt(0)" ::: "memory");
    __syncthreads();                                   // S4
    if (tid == 0){
      int v = t + 1;
      asm volatile("global_store_dword %0, %1, off sc0 sc1" :: "v"(fself), "v"(v) : "memory");
    }
  }
}

// ---------------- bf16 MFMA GEMM (R18 proven: XCD-chunked, 3-buf depth-2, 128²) ------
__global__ __launch_bounds__(256) void gemm_bf16(
    const unsigned short* __restrict__ A, const unsigned short* __restrict__ Bt,
    const float* __restrict__ bias, float* __restrict__ C,
    int M, int N, int K)
{
  __shared__ unsigned short lA[3][128*32], lB[3][128*32];
  const int tid = threadIdx.x;
  const int w = tid >> 6, l = tid & 63;
  const int wr = w >> 1, wc = w & 1;
  const int lr = l & 15, lk = l >> 4;
  const int orig = blockIdx.x;
  const int logical = (orig & 7)*500 + (orig >> 3);
  const int mt = logical & 15;
  const int nt = logical >> 4;
  const int brow = mt * 128, bcol = nt * 128;

  const int base0 = w*2048;
  const int base1 = w*2048 + 1024;
  const int L0 = base0 + l*16, L1 = base1 + l*16;
  const int Lg0 = L0 ^ (((L0 >> 7) & 3) << 4);
  const int Lg1 = L1 ^ (((L1 >> 7) & 3) << 4);
  const int row0 = Lg0 >> 6, kb0 = Lg0 & 63;
  const int row1 = Lg1 >> 6, kb1 = Lg1 & 63;

  f32x4 acc[4][4] = {};

  #define STAGE_KT(kt_, bu_) do{ \
    const int k0_ = (kt_) * 32; \
    gload_lds16((const char*)(A + (size_t)(brow+row0)*K + k0_) + kb0, (char*)lA[bu_] + base0); \
    gload_lds16((const char*)(Bt + (size_t)(bcol+row0)*K + k0_) + kb0, (char*)lB[bu_] + base0); \
    gload_lds16((const char*)(A + (size_t)(brow+row1)*K + k0_) + kb1, (char*)lA[bu_] + base1); \
    gload_lds16((const char*)(Bt + (size_t)(bcol+row1)*K + k0_) + kb1, (char*)lB[bu_] + base1); \
  }while(0)

  STAGE_KT(0, 0);
  STAGE_KT(1, 1);
  asm volatile("s_waitcnt vmcnt(4)" ::: "memory");
  __syncthreads();

  for (int kt = 0; kt < 32; ++kt){
    const int bu = kt - (kt / 3) * 3;
    if (kt < 30){
      const int nb = (kt + 2) - ((kt + 2) / 3) * 3;
      STAGE_KT(kt + 2, nb);
    }
    bf16x8 af[4], bfr[4];
    #pragma unroll
    for (int m = 0; m < 4; ++m){
      const int L = (wr*64 + m*16 + lr)*64 + lk*16;
      const int sp = L ^ (((L >> 7) & 3) << 4);
      af[m] = *(const bf16x8*)((char*)lA[bu] + sp);
    }
    #pragma unroll
    for (int n = 0; n < 4; ++n){
      const int L = (wc*64 + n*16 + lr)*64 + lk*16;
      const int sp = L ^ (((L >> 7) & 3) << 4);
      bfr[n] = *(const bf16x8*)((char*)lB[bu] + sp);
    }
    #pragma unroll
    for (int m = 0; m < 4; ++m)
      #pragma unroll
      for (int n = 0; n < 4; ++n)
        acc[m][n] = __builtin_amdgcn_mfma_f32_16x16x32_bf16(af[m], bfr[n], acc[m][n], 0, 0, 0);
    if (kt < 31){
      if (kt < 30) asm volatile("s_waitcnt vmcnt(4)" ::: "memory");
      else         asm volatile("s_waitcnt vmcnt(0)" ::: "memory");
      __syncthreads();
    }
  }
  #undef STAGE_KT

  #pragma unroll
  for (int m = 0; m < 4; ++m){
    #pragma unroll
    for (int n = 0; n < 4; ++n){
      const int col = bcol + wc*64 + n*16 + lr;
      const float bv = bias[col];
      const int row0_ = brow + wr*64 + m*16 + lk*4;
      #pragma unroll
      for (int r = 0; r < 4; ++r)
        C[(size_t)(row0_ + r)*N + col] = acc[m][n][r] + bv;
    }
  }
}

extern "C" void kernel_launch(void* const* d_in, const int* in_sizes, int n_in,
                              void* d_out, int out_size, void* d_ws, size_t ws_size,
                              hipStream_t stream){
  (void)in_sizes; (void)n_in; (void)out_size; (void)ws_size;
  const int*   seqs = (const int*)d_in[0];
  const float* emb  = (const float*)d_in[1];
  const float* fk0  = (const float*)d_in[2];
  const float* fr0  = (const float*)d_in[3];
  const float* fb0  = (const float*)d_in[4];
  const float* fk1  = (const float*)d_in[5];
  const float* fr1  = (const float*)d_in[6];
  const float* fb1  = (const float*)d_in[7];
  const float* bk0  = (const float*)d_in[8];
  const float* br0  = (const float*)d_in[9];
  const float* bb0  = (const float*)d_in[10];
  const float* bk1  = (const float*)d_in[11];
  const float* br1  = (const float*)d_in[12];
  const float* bb1  = (const float*)d_in[13];
  const float* Wp   = (const float*)d_in[14];
  const float* bp   = (const float*)d_in[15];
  float* out = (float*)d_out;

  char* ws = (char*)d_ws;
  size_t off = 0;
  auto alloc = [&](size_t b){ size_t o = off; off += (b + 255) & ~(size_t)255; return o; };
  int* flags            = (int*)(ws + alloc(4096));
  unsigned short* x     = (unsigned short*)(ws + alloc((size_t)16*130*256*2));
  int* mask             = (int*)(ws + alloc((size_t)16*130*4));
  unsigned short* fk0T  = (unsigned short*)(ws + alloc((size_t)2048*256*2));
  unsigned short* fr0T  = (unsigned short*)(ws + alloc((size_t)2048*512*2));
  unsigned short* fk1T  = (unsigned short*)(ws + alloc((size_t)2048*512*2));
  unsigned short* fr1T  = (unsigned short*)(ws + alloc((size_t)2048*512*2));
  unsigned short* bk0T  = (unsigned short*)(ws + alloc((size_t)2048*256*2));
  unsigned short* br0T  = (unsigned short*)(ws + alloc((size_t)2048*512*2));
  unsigned short* bk1T  = (unsigned short*)(ws + alloc((size_t)2048*512*2));
  unsigned short* br1T  = (unsigned short*)(ws + alloc((size_t)2048*512*2));
  unsigned short* h0f   = (unsigned short*)(ws + alloc((size_t)128*16*512*2));
  unsigned short* h0b   = (unsigned short*)(ws + alloc((size_t)128*16*512*2));
  unsigned short* aproj = (unsigned short*)(ws + alloc((size_t)2048*1024*2));
  unsigned short* WpT   = (unsigned short*)(ws + alloc((size_t)32000*1024*2));

  embed_prep<<<516, 512, 0, stream>>>(seqs, emb, x, mask, flags,
      fk0, fk0T, fr0, fr0T, fk1, fk1T, fr1, fr1T,
      bk0, bk0T, br0, br0T, bk1, bk1T, br1, br1T);

  lstm_coop<<<160, 512, 0, stream>>>(x, mask,
      fk0T, fr0T, fk1T, fr1T, bk0T, br0T, bk1T, br1T,
      fb0, fb1, bb0, bb1, Wp, WpT, h0f, h0b, aproj, flags);

  gemm_bf16<<<4000, 256, 0, stream>>>(aproj, WpT, bp, out, 2048, 32000, 1024);
}